// Round 3
// baseline (1187.126 us; speedup 1.0000x reference)
//
#include <hip/hip_runtime.h>
#include <math.h>

typedef float f32x4 __attribute__((ext_vector_type(4)));
typedef unsigned short u16x8 __attribute__((ext_vector_type(8)));
typedef unsigned short u16x4 __attribute__((ext_vector_type(4)));
typedef __bf16 bf16x8 __attribute__((ext_vector_type(8)));
typedef unsigned int u32;

#define DEV static __device__ __forceinline__

DEV unsigned short f2bf(float f) {            // RNE f32 -> bf16 bits
  unsigned u = __float_as_uint(f);
  u += 0x7FFFu + ((u >> 16) & 1u);
  return (unsigned short)(u >> 16);
}
DEV float bf2f(unsigned short s) { return __uint_as_float(((unsigned)s) << 16); }
DEV bf16x8 asbf(u16x8 v) { return __builtin_bit_cast(bf16x8, v); }

DEV void gload16(const void* g, void* l) {    // async global->LDS, 16B/lane, wave-uniform LDS base
  __builtin_amdgcn_global_load_lds((const __attribute__((address_space(1))) u32*)g,
                                   (__attribute__((address_space(3))) u32*)l, 16, 0, 0);
}

// ---------------------------------------------------------------- f32 -> bf16 bulk convert
__global__ void cvt_kernel(const float* __restrict__ in, unsigned short* __restrict__ out, int n8) {
  for (int i = blockIdx.x * 256 + threadIdx.x; i < n8; i += gridDim.x * 256) {
    const float* s = in + (size_t)i * 8;
    f32x4 a = *(const f32x4*)s, b = *(const f32x4*)(s + 4);
    u16x8 o;
    for (int j = 0; j < 4; ++j) { o[j] = f2bf(a[j]); o[j + 4] = f2bf(b[j]); }
    *(u16x8*)(out + (size_t)i * 8) = o;
  }
}

// ---------------------------------------------------------------- embed
__global__ void embed_kernel(const int* __restrict__ x, const float* __restrict__ tok,
                             const float* __restrict__ pos, float* __restrict__ h,
                             unsigned short* __restrict__ hbf) {
  int t = blockIdx.x, tid = threadIdx.x;
  int v = x[t], s = t & 1023;                 // S = 1024
  f32x4 a = *(const f32x4*)(tok + (size_t)v * 1024 + tid * 4);
  f32x4 b = *(const f32x4*)(pos + (size_t)s * 1024 + tid * 4);
  f32x4 r = a + b;
  *(f32x4*)(h + (size_t)t * 1024 + tid * 4) = r;
  u16x4 rb;
  for (int i = 0; i < 4; ++i) rb[i] = f2bf(r[i]);
  *(u16x4*)(hbf + (size_t)t * 1024 + tid * 4) = rb;
}

// ---------------------------------------------------------------- LayerNorm(preA + preB + res)
__global__ __launch_bounds__(256) void ln_kernel(const float* __restrict__ preA,
    const float* __restrict__ preB, const float* __restrict__ res,
    const float* __restrict__ g, const float* __restrict__ bta,
    float* __restrict__ outf, unsigned short* __restrict__ outbf) {
  int row = blockIdx.x, tid = threadIdx.x;
  size_t base = (size_t)row * 1024 + tid * 4;
  f32x4 xv = *(const f32x4*)(preA + base);
  xv += *(const f32x4*)(preB + base);
  xv += *(const f32x4*)(res + base);
  float s = xv[0] + xv[1] + xv[2] + xv[3];
  float s2 = xv[0]*xv[0] + xv[1]*xv[1] + xv[2]*xv[2] + xv[3]*xv[3];
  for (int m = 1; m < 64; m <<= 1) { s += __shfl_xor(s, m); s2 += __shfl_xor(s2, m); }
  __shared__ float red[8];
  int w = tid >> 6;
  if ((tid & 63) == 0) { red[w * 2] = s; red[w * 2 + 1] = s2; }
  __syncthreads();
  s = red[0] + red[2] + red[4] + red[6];
  s2 = red[1] + red[3] + red[5] + red[7];
  float mu = s * (1.f / 1024.f);
  float var = s2 * (1.f / 1024.f) - mu * mu;
  float rs = rsqrtf(var + 1e-5f);
  f32x4 gv = *(const f32x4*)(g + tid * 4);
  f32x4 bv = *(const f32x4*)(bta + tid * 4);
  f32x4 o; u16x4 ob;
  for (int i = 0; i < 4; ++i) { o[i] = (xv[i] - mu) * rs * gv[i] + bv[i]; ob[i] = f2bf(o[i]); }
  *(f32x4*)(outf + base) = o;
  *(u16x4*)(outbf + base) = ob;
}

// ---------------------------------------------------------------- QKV (shared 64x64 weight per head)
__global__ __launch_bounds__(256) void qkv_kernel(const unsigned short* __restrict__ hbf,
    const float* __restrict__ wq, const float* __restrict__ wk, const float* __restrict__ wv,
    unsigned short* __restrict__ q, unsigned short* __restrict__ k, unsigned short* __restrict__ v) {
  __shared__ float Wt[3][64 * 65];            // transposed [d][e], pad 65: conflict-free
  int tid = threadIdx.x;
  for (int j = 0; j < 16; ++j) {
    int idx = tid + 256 * j; int e = idx >> 6, d = idx & 63;
    Wt[0][d * 65 + e] = wq[idx];
    Wt[1][d * 65 + e] = wk[idx];
    Wt[2][d * 65 + e] = wv[idx];
  }
  __syncthreads();
  int lane = tid & 63, w = tid >> 6;
  for (int it = 0; it < 8; ++it) {
    int th = blockIdx.x * 32 + w * 8 + it;    // token-head in [0, 32768)
    int t = th >> 4, hh = th & 15;
    size_t off = (size_t)t * 1024 + hh * 64;
    float xv = bf2f(hbf[off + lane]);
    float aq = 0.f, ak = 0.f, av = 0.f;
    for (int d = 0; d < 64; ++d) {
      float xd = __shfl(xv, d);
      aq = fmaf(Wt[0][d * 65 + lane], xd, aq);
      ak = fmaf(Wt[1][d * 65 + lane], xd, ak);
      av = fmaf(Wt[2][d * 65 + lane], xd, av);
    }
    q[off + lane] = f2bf(aq);
    k[off + lane] = f2bf(ak);
    v[off + lane] = f2bf(av);
  }
}

// ---------------------------------------------------------------- V transpose: [b,s,h,e] -> [b,h,e,s]
__global__ __launch_bounds__(256) void vtrans_kernel(const unsigned short* __restrict__ v,
                                                     unsigned short* __restrict__ vt) {
  __shared__ unsigned short T[64 * 72];
  int tid = threadIdx.x, st = blockIdx.x, bh = blockIdx.y;
  int b = bh >> 4, hh = bh & 15;
  for (int j = 0; j < 2; ++j) {
    int idx = tid + 256 * j; int s = idx >> 3, e0 = (idx & 7) * 8;
    u16x8 r = *(const u16x8*)(v + ((size_t)(b * 1024 + st * 64 + s) * 16 + hh) * 64 + e0);
    for (int i = 0; i < 8; ++i) T[(e0 + i) * 72 + s] = r[i];
  }
  __syncthreads();
  for (int j = 0; j < 2; ++j) {
    int idx = tid + 256 * j; int e = idx >> 3, s0 = (idx & 7) * 8;
    u16x8 r = *(const u16x8*)(&T[e * 72 + s0]);
    *(u16x8*)(vt + ((size_t)(b * 16 + hh) * 64 + e) * 1024 + st * 64 + s0) = r;
  }
}

// ---------------------------------------------------------------- flash attention (no LDS K/V: L2-resident)
__global__ __launch_bounds__(256, 4) void attn_kernel(const unsigned short* __restrict__ qb,
    const unsigned short* __restrict__ kb, const unsigned short* __restrict__ vtb,
    unsigned short* __restrict__ ob) {
  constexpr int P = 72;
  __shared__ unsigned short Ps[4][16 * P];
  int tid = threadIdx.x, lane = tid & 63, w = tid >> 6;
  int l15 = lane & 15, lg = lane >> 4;
  int qt = blockIdx.x, bh = blockIdx.y, b = bh >> 4, hh = bh & 15;
  int q0 = qt * 64 + w * 16;
  const unsigned short* qrow = qb + ((size_t)(b * 1024 + q0 + l15) * 16 + hh) * 64 + lg * 8;
  bf16x8 qa0 = asbf(*(const u16x8*)qrow);
  bf16x8 qa1 = asbf(*(const u16x8*)(qrow + 32));
  const unsigned short* kfr = kb + ((size_t)(b * 1024 + l15) * 16 + hh) * 64 + lg * 8;
  const unsigned short* vfr = vtb + ((size_t)((b * 16 + hh) * 64) + l15) * 1024 + lg * 8;
  float m_[4] = {-1e30f, -1e30f, -1e30f, -1e30f};
  float ls[4] = {0.f, 0.f, 0.f, 0.f};
  f32x4 oacc[4] = {};
  const float inv = 1.f / 32.f;
  for (int kt = 0; kt < 16; ++kt) {
    f32x4 sf[4] = {};
    for (int n = 0; n < 4; ++n) {
      const unsigned short* kp = kfr + (size_t)(kt * 64 + n * 16) * 1024;
      bf16x8 k0 = asbf(*(const u16x8*)kp);
      bf16x8 k1 = asbf(*(const u16x8*)(kp + 32));
      sf[n] = __builtin_amdgcn_mfma_f32_16x16x32_bf16(qa0, k0, sf[n], 0, 0, 0);
      sf[n] = __builtin_amdgcn_mfma_f32_16x16x32_bf16(qa1, k1, sf[n], 0, 0, 0);
    }
    for (int n = 0; n < 4; ++n) sf[n] *= inv;
    float mx[4], sc[4];
    for (int r = 0; r < 4; ++r) {
      float t0 = fmaxf(fmaxf(sf[0][r], sf[1][r]), fmaxf(sf[2][r], sf[3][r]));
      for (int msk = 1; msk < 16; msk <<= 1) t0 = fmaxf(t0, __shfl_xor(t0, msk));
      mx[r] = fmaxf(m_[r], t0);
      sc[r] = __expf(m_[r] - mx[r]);
      m_[r] = mx[r];
    }
    float rsum[4] = {0.f, 0.f, 0.f, 0.f};
    unsigned short pb[4][4];
    for (int n = 0; n < 4; ++n)
      for (int r = 0; r < 4; ++r) {
        float pv = __expf(sf[n][r] - mx[r]);
        rsum[r] += pv;
        pb[n][r] = f2bf(pv);
      }
    for (int r = 0; r < 4; ++r) {
      float t0 = rsum[r];
      for (int msk = 1; msk < 16; msk <<= 1) t0 += __shfl_xor(t0, msk);
      ls[r] = ls[r] * sc[r] + t0;
    }
    for (int n = 0; n < 4; ++n)
      for (int r = 0; r < 4; ++r) oacc[n][r] *= sc[r];
    unsigned short* pw = Ps[w];                // per-wave region: no barrier needed
    for (int n = 0; n < 4; ++n)
      for (int r = 0; r < 4; ++r)
        pw[(4 * lg + r) * P + n * 16 + l15] = pb[n][r];
    asm volatile("s_waitcnt lgkmcnt(0)" ::: "memory");
    bf16x8 pa0 = asbf(*(const u16x8*)(&pw[l15 * P + lg * 8]));
    bf16x8 pa1 = asbf(*(const u16x8*)(&pw[l15 * P + 32 + lg * 8]));
    for (int n = 0; n < 4; ++n) {
      const unsigned short* vp = vfr + (size_t)(n * 16) * 1024 + kt * 64;
      bf16x8 v0 = asbf(*(const u16x8*)vp);
      bf16x8 v1 = asbf(*(const u16x8*)(vp + 32));
      oacc[n] = __builtin_amdgcn_mfma_f32_16x16x32_bf16(pa0, v0, oacc[n], 0, 0, 0);
      oacc[n] = __builtin_amdgcn_mfma_f32_16x16x32_bf16(pa1, v1, oacc[n], 0, 0, 0);
    }
  }
  for (int n = 0; n < 4; ++n)
    for (int r = 0; r < 4; ++r) {
      float o = oacc[n][r] / ls[r];
      ob[((size_t)(b * 1024 + q0 + 4 * lg + r) * 16 + hh) * 64 + n * 16 + l15] = f2bf(o);
    }
}

// ---------------------------------------------------------------- bf16 GEMM, m97 structure (layer GEMMs)
template <int BM, int KSPLIT, int EPI>
__global__ __launch_bounds__(256) void gemm_kernel(
    const unsigned short* __restrict__ A, int lda,
    const unsigned short* __restrict__ B, int ldb,
    const float* __restrict__ bias,
    float* __restrict__ CfA, float* __restrict__ CfB, unsigned short* __restrict__ Cb,
    int ldc, int Ksub) {
  constexpr int LOGMT = (BM == 128) ? 4 : 5;  // M = 2048 always
  constexpr int MT = 2048 / BM;
  constexpr int MI = BM / 32;                 // A-frags per wave
  __shared__ alignas(16) char smem[33280];    // max(stage 32KB, Cs 64*130*4)
  unsigned short* As = (unsigned short*)smem;           // [2][BM*32]
  unsigned short* Bs = As + 2 * BM * 32;                // [2][128*32]
  float* Cs = (float*)smem;                             // epilogue bounce, stride 130

  int wg = blockIdx.x;
  int mt = wg & (MT - 1);
  int rest = wg >> LOGMT;
  int nt, kh;
  if (KSPLIT == 2) { nt = rest & 7; kh = rest >> 3; }   // NT must be 8 when split
  else { nt = rest; kh = 0; }
  int m0 = mt * BM, n0 = nt * 128;
  const unsigned short* Ae = A + (KSPLIT == 2 ? (size_t)kh * Ksub : 0);
  const unsigned short* Be = B + (KSPLIT == 2 ? (size_t)kh * Ksub : 0);

  int tid = threadIdx.x, ln = tid & 63, wv = tid >> 6;
  int l15 = ln & 15, lg = ln >> 4;
  int wm = (wv >> 1) * (BM / 2), wn = (wv & 1) * 64;

  auto stage = [&](int buf, int k0) {
    for (int j = 0; j < BM / 64; ++j) {
      int row = j * 64 + wv * 16 + (ln >> 2);
      gload16(Ae + (size_t)(m0 + row) * lda + k0 + (ln & 3) * 8,
              &As[buf * (BM * 32) + (j * 64 + wv * 16) * 32]);
    }
    for (int j = 0; j < 2; ++j) {
      int row = j * 64 + wv * 16 + (ln >> 2);
      gload16(Be + (size_t)(n0 + row) * ldb + k0 + (ln & 3) * 8,
              &Bs[buf * 4096 + (j * 64 + wv * 16) * 32]);
    }
  };

  f32x4 acc[MI][4] = {};
  auto compute = [&](int buf) {
    const unsigned short* as = &As[buf * (BM * 32)];
    const unsigned short* bs = &Bs[buf * 4096];
    bf16x8 af[MI], bfn[4];
    for (int mi = 0; mi < MI; ++mi)
      af[mi] = asbf(*(const u16x8*)&as[(wm + mi * 16 + l15) * 32 + lg * 8]);
    for (int ni = 0; ni < 4; ++ni)
      bfn[ni] = asbf(*(const u16x8*)&bs[(wn + ni * 16 + l15) * 32 + lg * 8]);
    for (int mi = 0; mi < MI; ++mi)
      for (int ni = 0; ni < 4; ++ni)
        acc[mi][ni] = __builtin_amdgcn_mfma_f32_16x16x32_bf16(af[mi], bfn[ni], acc[mi][ni], 0, 0, 0);
  };

  stage(0, 0);
  __syncthreads();
  int ntk = Ksub >> 5, cur = 0;
  for (int t = 0; t < ntk - 1; ++t) {
    stage(cur ^ 1, (t + 1) << 5);
    compute(cur);
    __syncthreads();
    cur ^= 1;
  }
  compute(cur);

  float* Cf = (kh == 0) ? CfA : CfB;
  const bool addb = (kh == 0);
  for (int p = 0; p < BM / 64; ++p) {
    __syncthreads();
    if ((wm >> 6) == p) {
      int rb = wm & 63;
      for (int mi = 0; mi < MI; ++mi)
        for (int ni = 0; ni < 4; ++ni) {
          int cn = wn + ni * 16 + l15;
          float bv = addb ? bias[n0 + cn] : 0.f;
          for (int r = 0; r < 4; ++r) {
            float vv = acc[mi][ni][r] + bv;
            if (EPI == 1) vv = 0.5f * vv * (1.f + erff(vv * 0.70710678118f));
            Cs[(rb + mi * 16 + 4 * lg + r) * 130 + cn] = vv;
          }
        }
    }
    __syncthreads();
    int row = tid >> 3;
    for (int ri = 0; ri < 2; ++ri) {
      int lr = ri * 32 + row;
      size_t gbase = (size_t)(m0 + p * 64 + lr) * ldc + n0;
      if (EPI == 0) {
        int c4 = (tid & 7) * 4;
        for (int j = 0; j < 4; ++j)
          *(f32x4*)(Cf + gbase + c4 + j * 32) = *(const f32x4*)&Cs[lr * 130 + c4 + j * 32];
      } else {
        for (int j = 0; j < 2; ++j) {
          int cc = (tid & 7) * 8 + j * 64;
          f32x4 v0 = *(const f32x4*)&Cs[lr * 130 + cc];
          f32x4 v1 = *(const f32x4*)&Cs[lr * 130 + cc + 4];
          u16x8 o;
          for (int i = 0; i < 4; ++i) { o[i] = f2bf(v0[i]); o[i + 4] = f2bf(v1[i]); }
          *(u16x8*)(Cb + gbase + cc) = o;
        }
      }
    }
  }
}

// ---------------------------------------------------------------- 256x256 8-phase GEMM (logits)
// C = A @ B^T + bias. A:[2048,K] bf16, B:[N,K] bf16, C f32 [2048,ldc]. grid = 8*(N/256), 512 thr.
// LDS 128KiB dynamic: A bufs [2][256x64] @0, B bufs @32768 elems. XOR-swizzle (row&7)<<4 on bytes.
__global__ __launch_bounds__(512, 2) void gemm256_kernel(
    const unsigned short* __restrict__ A, int lda,
    const unsigned short* __restrict__ B, int ldb,
    const float* __restrict__ bias, float* __restrict__ C, int ldc, int K) {
  extern __shared__ unsigned short sm[];      // 65536 elems = 128 KiB
  int b = blockIdx.x;
  int c = (int)gridDim.x >> 3;
  int wg = (b & 7) * c + (b >> 3);            // XCD-contiguous
  int mt = wg & 7, nt = wg >> 3;
  int m0 = mt * 256, n0 = nt * 256;

  int tid = threadIdx.x, ln = tid & 63, wv = tid >> 6;
  int l15 = ln & 15, lg = ln >> 4;
  int wm = wv >> 2, wn = wv & 3;              // 2M x 4N waves; wave tile 128x64

  // stage bases: thread covers row tid>>3 (of 64-row chunk), swizzled col-block
  const unsigned short* Ab = A + (size_t)(m0 + (tid >> 3)) * lda + (((tid & 7) ^ ((tid >> 3) & 7)) * 8);
  const unsigned short* Bb = B + (size_t)(n0 + (tid >> 3)) * ldb + (((tid & 7) ^ ((tid >> 3) & 7)) * 8);
  auto stA = [&](int bt, int j, int k0) {
    gload16(Ab + (size_t)j * 64 * lda + k0, &sm[bt * 16384 + j * 4096 + wv * 512]);
  };
  auto stB = [&](int bt, int j, int k0) {
    gload16(Bb + (size_t)j * 64 * ldb + k0, &sm[32768 + bt * 16384 + j * 4096 + wv * 512]);
  };

  // LDS frag reads (swizzled): elem = row*64 + ((ks*4+lg)^(l15&7))*8
  int eA = (wm * 128 + l15) * 64;
  int eB = 32768 + (wn * 64 + l15) * 64;
  int xs0 = ((lg) ^ (l15 & 7)) * 8;
  int xs1 = ((4 + lg) ^ (l15 & 7)) * 8;
  auto ldsA = [&](int bt, int mi, int ks) -> bf16x8 {
    return asbf(*(const u16x8*)&sm[bt * 16384 + eA + mi * 1024 + (ks ? xs1 : xs0)]);
  };
  auto ldsB = [&](int bt, int ni, int ks) -> bf16x8 {
    return asbf(*(const u16x8*)&sm[bt * 16384 + eB + ni * 1024 + (ks ? xs1 : xs0)]);
  };

  f32x4 acc[8][4] = {};
  bf16x8 Bfr[4][2];
  auto MM = [&](int mi, bf16x8 a0, bf16x8 a1) {
#pragma unroll
    for (int ni = 0; ni < 4; ++ni) {
      acc[mi][ni] = __builtin_amdgcn_mfma_f32_16x16x32_bf16(a0, Bfr[ni][0], acc[mi][ni], 0, 0, 0);
      acc[mi][ni] = __builtin_amdgcn_mfma_f32_16x16x32_bf16(a1, Bfr[ni][1], acc[mi][ni], 0, 0, 0);
    }
  };

#define PH_BAR() __builtin_amdgcn_sched_barrier(0); __builtin_amdgcn_s_barrier(); \
  asm volatile("s_waitcnt lgkmcnt(0)" ::: "memory"); __builtin_amdgcn_sched_barrier(0)
#define PH_END() __builtin_amdgcn_sched_barrier(0); __builtin_amdgcn_s_barrier()

  // prologue: B0..3, A0, A2, A1, A3 of tile 0; first consumers need all but A1,A3
  stB(0, 0, 0); stB(0, 1, 0); stB(0, 2, 0); stB(0, 3, 0);
  stA(0, 0, 0); stA(0, 2, 0); stA(0, 1, 0); stA(0, 3, 0);
  asm volatile("s_waitcnt vmcnt(2)" ::: "memory");
  __builtin_amdgcn_s_barrier();

  int ntk = K >> 6;
  for (int t = 0; t < ntk; ++t) {
    int bt = t & 1, nb = bt ^ 1;
    bool pf = (t + 1 < ntk);
    int k1 = (t + 1) << 6;
    { // phase 0: B frags + A mi0-1; stage B'0,B'1
#pragma unroll
      for (int ni = 0; ni < 4; ++ni) { Bfr[ni][0] = ldsB(bt, ni, 0); Bfr[ni][1] = ldsB(bt, ni, 1); }
      bf16x8 a00 = ldsA(bt, 0, 0), a01 = ldsA(bt, 0, 1);
      bf16x8 a10 = ldsA(bt, 1, 0), a11 = ldsA(bt, 1, 1);
      if (pf) { stB(nb, 0, k1); stB(nb, 1, k1); }
      PH_BAR();
      __builtin_amdgcn_s_setprio(1);
      MM(0, a00, a01); MM(1, a10, a11);
      __builtin_amdgcn_s_setprio(0);
      PH_END();
    }
    { // phase 1: A mi2-3; stage B'2,B'3; wait A1,A3 of current tile
      bf16x8 a00 = ldsA(bt, 2, 0), a01 = ldsA(bt, 2, 1);
      bf16x8 a10 = ldsA(bt, 3, 0), a11 = ldsA(bt, 3, 1);
      if (pf) { stB(nb, 2, k1); stB(nb, 3, k1); asm volatile("s_waitcnt vmcnt(4)" ::: "memory"); }
      else    { asm volatile("s_waitcnt vmcnt(0)" ::: "memory"); }
      PH_BAR();
      __builtin_amdgcn_s_setprio(1);
      MM(2, a00, a01); MM(3, a10, a11);
      __builtin_amdgcn_s_setprio(0);
      PH_END();
    }
    { // phase 2: A mi4-5; stage A'0,A'2
      bf16x8 a00 = ldsA(bt, 4, 0), a01 = ldsA(bt, 4, 1);
      bf16x8 a10 = ldsA(bt, 5, 0), a11 = ldsA(bt, 5, 1);
      if (pf) { stA(nb, 0, k1); stA(nb, 2, k1); }
      PH_BAR();
      __builtin_amdgcn_s_setprio(1);
      MM(4, a00, a01); MM(5, a10, a11);
      __builtin_amdgcn_s_setprio(0);
      PH_END();
    }
    { // phase 3: A mi6-7; stage A'1,A'3; wait next tile's B+A0,A2
      bf16x8 a00 = ldsA(bt, 6, 0), a01 = ldsA(bt, 6, 1);
      bf16x8 a10 = ldsA(bt, 7, 0), a11 = ldsA(bt, 7, 1);
      if (pf) { stA(nb, 1, k1); stA(nb, 3, k1); asm volatile("s_waitcnt vmcnt(2)" ::: "memory"); }
      PH_BAR();
      __builtin_amdgcn_s_setprio(1);
      MM(6, a00, a01); MM(7, a10, a11);
      __builtin_amdgcn_s_setprio(0);
      PH_END();
    }
  }
#undef PH_BAR
#undef PH_END

  // epilogue: bias + direct stores (64B segments per quarter-wave)
#pragma unroll
  for (int ni = 0; ni < 4; ++ni) {
    int col = n0 + wn * 64 + ni * 16 + l15;
    float bv = bias[col];
#pragma unroll
    for (int mi = 0; mi < 8; ++mi) {
      int row = m0 + wm * 128 + mi * 16 + lg * 4;
#pragma unroll
      for (int r = 0; r < 4; ++r)
        C[(size_t)(row + r) * ldc + col] = acc[mi][ni][r] + bv;
    }
  }
}

// ----------------------------------------------------------------
extern "C" void kernel_launch(void* const* d_in, const int* in_sizes, int n_in,
                              void* d_out, int out_size, void* d_ws, size_t ws_size,
                              hipStream_t stream) {
  const int* x = (const int*)d_in[0];
  const float* tok = (const float*)d_in[1];
  const float* pos = (const float*)d_in[2];
  const float* wq = (const float*)d_in[3];
  const float* wk = (const float*)d_in[4];
  const float* wv = (const float*)d_in[5];
  const float* wo = (const float*)d_in[6];
  const float* bo = (const float*)d_in[7];
  const float* ln1g = (const float*)d_in[8];
  const float* ln1b = (const float*)d_in[9];
  const float* ln2g = (const float*)d_in[10];
  const float* ln2b = (const float*)d_in[11];
  const float* w1 = (const float*)d_in[12];
  const float* b1 = (const float*)d_in[13];
  const float* w2 = (const float*)d_in[14];
  const float* b2 = (const float*)d_in[15];
  const float* outw = (const float*)d_in[16];
  const float* outb = (const float*)d_in[17];
  float* out = (float*)d_out;

  const size_t MiB = 1 << 20;
  const size_t need = 4 * MiB + 65536000;
  if (ws_size < need) return;
  char* base = (char*)d_ws;
  unsigned short* hbf = (unsigned short*)base;            // 4 MiB, persistent
  char* R = base + 4 * MiB;
  float* hf  = (float*)(R);                               // 8 MiB
  float* x1f = (float*)(R + 8 * MiB);                     // 8 MiB
  unsigned short* x1bf = (unsigned short*)(R + 16 * MiB); // 4 MiB
  float* cfA = (float*)(R + 20 * MiB);                    // 8 MiB
  float* cfB = (float*)(R + 28 * MiB);                    // 8 MiB
  unsigned short* qs = (unsigned short*)(R + 36 * MiB);   // 6 slots x 4 MiB
  const size_t SL = 2048ull * 1024;
  unsigned short* qbf = qs;
  unsigned short* kbf = qs + SL;
  unsigned short* vbf = qs + 2 * SL;                      // also attn-out
  unsigned short* vtbf = qs + 3 * SL;                     // also wobf
  unsigned short* wobf = vtbf;
  unsigned short* w1bf = qbf;
  unsigned short* w2bf = qbf;
  unsigned short* ffbf = vbf;
  unsigned short* outwbf = (unsigned short*)R;            // 62.5 MiB, after layers

  embed_kernel<<<2048, 256, 0, stream>>>(x, tok, pos, hf, hbf);
  for (int l = 0; l < 4; ++l) {
    qkv_kernel<<<1024, 256, 0, stream>>>(hbf, wq + l * 4096, wk + l * 4096, wv + l * 4096,
                                         qbf, kbf, vbf);
    vtrans_kernel<<<dim3(16, 32), 256, 0, stream>>>(vbf, vtbf);
    attn_kernel<<<dim3(16, 32), 256, 0, stream>>>(qbf, kbf, vtbf, vbf);
    cvt_kernel<<<512, 256, 0, stream>>>(wo + (size_t)l * 1048576, wobf, 131072);
    cvt_kernel<<<2048, 256, 0, stream>>>(w1 + (size_t)l * 4194304, w1bf, 524288);
    gemm_kernel<64, 2, 0><<<512, 256, 0, stream>>>(
        vbf, 1024, wobf, 1024, bo + l * 1024, cfA, cfB, nullptr, 1024, 512);
    ln_kernel<<<2048, 256, 0, stream>>>(cfA, cfB, hf, ln1g + l * 1024, ln1b + l * 1024,
                                        x1f, x1bf);
    gemm_kernel<128, 1, 1><<<512, 256, 0, stream>>>(
        x1bf, 1024, w1bf, 1024, b1 + l * 4096, nullptr, nullptr, ffbf, 4096, 1024);
    cvt_kernel<<<2048, 256, 0, stream>>>(w2 + (size_t)l * 4194304, w2bf, 524288);
    gemm_kernel<64, 2, 0><<<512, 256, 0, stream>>>(
        ffbf, 4096, w2bf, 4096, b2 + l * 1024, cfA, cfB, nullptr, 1024, 2048);
    ln_kernel<<<2048, 256, 0, stream>>>(cfA, cfB, x1f, ln2g + l * 1024, ln2b + l * 1024,
                                        hf, hbf);
  }
  cvt_kernel<<<2048, 256, 0, stream>>>(outw, outwbf, 4096000);
  gemm256_kernel<<<1000, 512, 131072, stream>>>(hbf, 1024, outwbf, 1024, outb, out, 32000, 1024);
}

// Round 4
// 1137.622 us; speedup vs baseline: 1.0435x; 1.0435x over previous
//
#include <hip/hip_runtime.h>
#include <math.h>

typedef float f32x4 __attribute__((ext_vector_type(4)));
typedef unsigned short u16x8 __attribute__((ext_vector_type(8)));
typedef unsigned short u16x4 __attribute__((ext_vector_type(4)));
typedef __bf16 bf16x8 __attribute__((ext_vector_type(8)));
typedef unsigned int u32;

#define DEV static __device__ __forceinline__

DEV unsigned short f2bf(float f) {            // RNE f32 -> bf16 bits
  unsigned u = __float_as_uint(f);
  u += 0x7FFFu + ((u >> 16) & 1u);
  return (unsigned short)(u >> 16);
}
DEV float bf2f(unsigned short s) { return __uint_as_float(((unsigned)s) << 16); }
DEV bf16x8 asbf(u16x8 v) { return __builtin_bit_cast(bf16x8, v); }

DEV void gload16(const void* g, void* l) {    // async global->LDS, 16B/lane, wave-uniform LDS base
  __builtin_amdgcn_global_load_lds((const __attribute__((address_space(1))) u32*)g,
                                   (__attribute__((address_space(3))) u32*)l, 16, 0, 0);
}

// ---------------------------------------------------------------- f32 -> bf16 bulk convert
__global__ void cvt_kernel(const float* __restrict__ in, unsigned short* __restrict__ out, int n8) {
  for (int i = blockIdx.x * 256 + threadIdx.x; i < n8; i += gridDim.x * 256) {
    const float* s = in + (size_t)i * 8;
    f32x4 a = *(const f32x4*)s, b = *(const f32x4*)(s + 4);
    u16x8 o;
    for (int j = 0; j < 4; ++j) { o[j] = f2bf(a[j]); o[j + 4] = f2bf(b[j]); }
    *(u16x8*)(out + (size_t)i * 8) = o;
  }
}

// ---------------------------------------------------------------- embed
__global__ void embed_kernel(const int* __restrict__ x, const float* __restrict__ tok,
                             const float* __restrict__ pos, float* __restrict__ h,
                             unsigned short* __restrict__ hbf) {
  int t = blockIdx.x, tid = threadIdx.x;
  int v = x[t], s = t & 1023;                 // S = 1024
  f32x4 a = *(const f32x4*)(tok + (size_t)v * 1024 + tid * 4);
  f32x4 b = *(const f32x4*)(pos + (size_t)s * 1024 + tid * 4);
  f32x4 r = a + b;
  *(f32x4*)(h + (size_t)t * 1024 + tid * 4) = r;
  u16x4 rb;
  for (int i = 0; i < 4; ++i) rb[i] = f2bf(r[i]);
  *(u16x4*)(hbf + (size_t)t * 1024 + tid * 4) = rb;
}

// ---------------------------------------------------------------- LayerNorm(preA + preB + res)
__global__ __launch_bounds__(256) void ln_kernel(const float* __restrict__ preA,
    const float* __restrict__ preB, const float* __restrict__ res,
    const float* __restrict__ g, const float* __restrict__ bta,
    float* __restrict__ outf, unsigned short* __restrict__ outbf) {
  int row = blockIdx.x, tid = threadIdx.x;
  size_t base = (size_t)row * 1024 + tid * 4;
  f32x4 xv = *(const f32x4*)(preA + base);
  xv += *(const f32x4*)(preB + base);
  xv += *(const f32x4*)(res + base);
  float s = xv[0] + xv[1] + xv[2] + xv[3];
  float s2 = xv[0]*xv[0] + xv[1]*xv[1] + xv[2]*xv[2] + xv[3]*xv[3];
  for (int m = 1; m < 64; m <<= 1) { s += __shfl_xor(s, m); s2 += __shfl_xor(s2, m); }
  __shared__ float red[8];
  int w = tid >> 6;
  if ((tid & 63) == 0) { red[w * 2] = s; red[w * 2 + 1] = s2; }
  __syncthreads();
  s = red[0] + red[2] + red[4] + red[6];
  s2 = red[1] + red[3] + red[5] + red[7];
  float mu = s * (1.f / 1024.f);
  float var = s2 * (1.f / 1024.f) - mu * mu;
  float rs = rsqrtf(var + 1e-5f);
  f32x4 gv = *(const f32x4*)(g + tid * 4);
  f32x4 bv = *(const f32x4*)(bta + tid * 4);
  f32x4 o; u16x4 ob;
  for (int i = 0; i < 4; ++i) { o[i] = (xv[i] - mu) * rs * gv[i] + bv[i]; ob[i] = f2bf(o[i]); }
  *(f32x4*)(outf + base) = o;
  *(u16x4*)(outbf + base) = ob;
}

// ---------------------------------------------------------------- QKV (shared 64x64 weight per head)
__global__ __launch_bounds__(256) void qkv_kernel(const unsigned short* __restrict__ hbf,
    const float* __restrict__ wq, const float* __restrict__ wk, const float* __restrict__ wv,
    unsigned short* __restrict__ q, unsigned short* __restrict__ k, unsigned short* __restrict__ v) {
  __shared__ float Wt[3][64 * 65];            // transposed [d][e], pad 65: conflict-free
  int tid = threadIdx.x;
  for (int j = 0; j < 16; ++j) {
    int idx = tid + 256 * j; int e = idx >> 6, d = idx & 63;
    Wt[0][d * 65 + e] = wq[idx];
    Wt[1][d * 65 + e] = wk[idx];
    Wt[2][d * 65 + e] = wv[idx];
  }
  __syncthreads();
  int lane = tid & 63, w = tid >> 6;
  for (int it = 0; it < 8; ++it) {
    int th = blockIdx.x * 32 + w * 8 + it;    // token-head in [0, 32768)
    int t = th >> 4, hh = th & 15;
    size_t off = (size_t)t * 1024 + hh * 64;
    float xv = bf2f(hbf[off + lane]);
    float aq = 0.f, ak = 0.f, av = 0.f;
    for (int d = 0; d < 64; ++d) {
      float xd = __shfl(xv, d);
      aq = fmaf(Wt[0][d * 65 + lane], xd, aq);
      ak = fmaf(Wt[1][d * 65 + lane], xd, ak);
      av = fmaf(Wt[2][d * 65 + lane], xd, av);
    }
    q[off + lane] = f2bf(aq);
    k[off + lane] = f2bf(ak);
    v[off + lane] = f2bf(av);
  }
}

// ---------------------------------------------------------------- V transpose: [b,s,h,e] -> [b,h,e,s]
__global__ __launch_bounds__(256) void vtrans_kernel(const unsigned short* __restrict__ v,
                                                     unsigned short* __restrict__ vt) {
  __shared__ unsigned short T[64 * 72];
  int tid = threadIdx.x, st = blockIdx.x, bh = blockIdx.y;
  int b = bh >> 4, hh = bh & 15;
  for (int j = 0; j < 2; ++j) {
    int idx = tid + 256 * j; int s = idx >> 3, e0 = (idx & 7) * 8;
    u16x8 r = *(const u16x8*)(v + ((size_t)(b * 1024 + st * 64 + s) * 16 + hh) * 64 + e0);
    for (int i = 0; i < 8; ++i) T[(e0 + i) * 72 + s] = r[i];
  }
  __syncthreads();
  for (int j = 0; j < 2; ++j) {
    int idx = tid + 256 * j; int e = idx >> 3, s0 = (idx & 7) * 8;
    u16x8 r = *(const u16x8*)(&T[e * 72 + s0]);
    *(u16x8*)(vt + ((size_t)(b * 16 + hh) * 64 + e) * 1024 + st * 64 + s0) = r;
  }
}

// ---------------------------------------------------------------- flash attention (round-2 LDS-staged version)
__global__ __launch_bounds__(256, 2) void attn_kernel(const unsigned short* __restrict__ qb,
    const unsigned short* __restrict__ kb, const unsigned short* __restrict__ vtb,
    unsigned short* __restrict__ ob) {
  constexpr int P = 72;                       // padded LDS stride (bf16 elems)
  __shared__ unsigned short Ks[64 * P], Vs[64 * P], Ps[4][16 * P];
  int tid = threadIdx.x, lane = tid & 63, w = tid >> 6;
  int l15 = lane & 15, lg = lane >> 4;
  int qt = blockIdx.x, bh = blockIdx.y, b = bh >> 4, hh = bh & 15;
  int q0 = qt * 64 + w * 16;
  const unsigned short* qrow = qb + ((size_t)(b * 1024 + q0 + l15) * 16 + hh) * 64 + lg * 8;
  bf16x8 qa0 = asbf(*(const u16x8*)qrow);
  bf16x8 qa1 = asbf(*(const u16x8*)(qrow + 32));
  float m_[4] = {-1e30f, -1e30f, -1e30f, -1e30f};
  float ls[4] = {0.f, 0.f, 0.f, 0.f};
  f32x4 oacc[4] = {};
  const float inv = 1.f / 32.f;
  for (int kt = 0; kt < 16; ++kt) {
    for (int j = 0; j < 2; ++j) {
      int idx = tid + 256 * j; int r = idx >> 3, c0 = (idx & 7) * 8;
      *(u16x8*)(&Ks[r * P + c0]) =
          *(const u16x8*)(kb + ((size_t)(b * 1024 + kt * 64 + r) * 16 + hh) * 64 + c0);
      *(u16x8*)(&Vs[r * P + c0]) =
          *(const u16x8*)(vtb + ((size_t)(b * 16 + hh) * 64 + r) * 1024 + kt * 64 + c0);
    }
    __syncthreads();
    f32x4 sf[4] = {};
    for (int n = 0; n < 4; ++n) {
      bf16x8 k0 = asbf(*(const u16x8*)(&Ks[(n * 16 + l15) * P + lg * 8]));
      bf16x8 k1 = asbf(*(const u16x8*)(&Ks[(n * 16 + l15) * P + 32 + lg * 8]));
      sf[n] = __builtin_amdgcn_mfma_f32_16x16x32_bf16(qa0, k0, sf[n], 0, 0, 0);
      sf[n] = __builtin_amdgcn_mfma_f32_16x16x32_bf16(qa1, k1, sf[n], 0, 0, 0);
    }
    for (int n = 0; n < 4; ++n) sf[n] *= inv;
    float mx[4], sc[4];
    for (int r = 0; r < 4; ++r) {
      float t0 = fmaxf(fmaxf(sf[0][r], sf[1][r]), fmaxf(sf[2][r], sf[3][r]));
      for (int msk = 1; msk < 16; msk <<= 1) t0 = fmaxf(t0, __shfl_xor(t0, msk));
      mx[r] = fmaxf(m_[r], t0);
      sc[r] = __expf(m_[r] - mx[r]);
      m_[r] = mx[r];
    }
    float rsum[4] = {0.f, 0.f, 0.f, 0.f};
    unsigned short pb[4][4];
    for (int n = 0; n < 4; ++n)
      for (int r = 0; r < 4; ++r) {
        float pv = __expf(sf[n][r] - mx[r]);
        rsum[r] += pv;
        pb[n][r] = f2bf(pv);
      }
    for (int r = 0; r < 4; ++r) {
      float t0 = rsum[r];
      for (int msk = 1; msk < 16; msk <<= 1) t0 += __shfl_xor(t0, msk);
      ls[r] = ls[r] * sc[r] + t0;
    }
    for (int n = 0; n < 4; ++n)
      for (int r = 0; r < 4; ++r) oacc[n][r] *= sc[r];
    unsigned short* pw = Ps[w];                // per-wave region: no barrier needed
    for (int n = 0; n < 4; ++n)
      for (int r = 0; r < 4; ++r)
        pw[(4 * lg + r) * P + n * 16 + l15] = pb[n][r];
    asm volatile("s_waitcnt lgkmcnt(0)" ::: "memory");
    bf16x8 pa0 = asbf(*(const u16x8*)(&pw[l15 * P + lg * 8]));
    bf16x8 pa1 = asbf(*(const u16x8*)(&pw[l15 * P + 32 + lg * 8]));
    for (int n = 0; n < 4; ++n) {
      bf16x8 v0 = asbf(*(const u16x8*)(&Vs[(n * 16 + l15) * P + lg * 8]));
      bf16x8 v1 = asbf(*(const u16x8*)(&Vs[(n * 16 + l15) * P + 32 + lg * 8]));
      oacc[n] = __builtin_amdgcn_mfma_f32_16x16x32_bf16(pa0, v0, oacc[n], 0, 0, 0);
      oacc[n] = __builtin_amdgcn_mfma_f32_16x16x32_bf16(pa1, v1, oacc[n], 0, 0, 0);
    }
    __syncthreads();
  }
  for (int n = 0; n < 4; ++n)
    for (int r = 0; r < 4; ++r) {
      float o = oacc[n][r] / ls[r];
      ob[((size_t)(b * 1024 + q0 + 4 * lg + r) * 16 + hh) * 64 + n * 16 + l15] = f2bf(o);
    }
}

// ---------------------------------------------------------------- bf16 GEMM, m97 structure (layer GEMMs)
template <int BM, int KSPLIT, int EPI>
__global__ __launch_bounds__(256) void gemm_kernel(
    const unsigned short* __restrict__ A, int lda,
    const unsigned short* __restrict__ B, int ldb,
    const float* __restrict__ bias,
    float* __restrict__ CfA, float* __restrict__ CfB, unsigned short* __restrict__ Cb,
    int ldc, int Ksub) {
  constexpr int LOGMT = (BM == 128) ? 4 : 5;  // M = 2048 always
  constexpr int MT = 2048 / BM;
  constexpr int MI = BM / 32;                 // A-frags per wave
  __shared__ alignas(16) char smem[33280];    // max(stage 32KB, Cs 64*130*4)
  unsigned short* As = (unsigned short*)smem;           // [2][BM*32]
  unsigned short* Bs = As + 2 * BM * 32;                // [2][128*32]
  float* Cs = (float*)smem;                             // epilogue bounce, stride 130

  int wg = blockIdx.x;
  int mt = wg & (MT - 1);
  int rest = wg >> LOGMT;
  int nt, kh;
  if (KSPLIT == 2) { nt = rest & 7; kh = rest >> 3; }   // NT must be 8 when split
  else { nt = rest; kh = 0; }
  int m0 = mt * BM, n0 = nt * 128;
  const unsigned short* Ae = A + (KSPLIT == 2 ? (size_t)kh * Ksub : 0);
  const unsigned short* Be = B + (KSPLIT == 2 ? (size_t)kh * Ksub : 0);

  int tid = threadIdx.x, ln = tid & 63, wv = tid >> 6;
  int l15 = ln & 15, lg = ln >> 4;
  int wm = (wv >> 1) * (BM / 2), wn = (wv & 1) * 64;

  auto stage = [&](int buf, int k0) {
    for (int j = 0; j < BM / 64; ++j) {
      int row = j * 64 + wv * 16 + (ln >> 2);
      gload16(Ae + (size_t)(m0 + row) * lda + k0 + (ln & 3) * 8,
              &As[buf * (BM * 32) + (j * 64 + wv * 16) * 32]);
    }
    for (int j = 0; j < 2; ++j) {
      int row = j * 64 + wv * 16 + (ln >> 2);
      gload16(Be + (size_t)(n0 + row) * ldb + k0 + (ln & 3) * 8,
              &Bs[buf * 4096 + (j * 64 + wv * 16) * 32]);
    }
  };

  f32x4 acc[MI][4] = {};
  auto compute = [&](int buf) {
    const unsigned short* as = &As[buf * (BM * 32)];
    const unsigned short* bs = &Bs[buf * 4096];
    bf16x8 af[MI], bfn[4];
    for (int mi = 0; mi < MI; ++mi)
      af[mi] = asbf(*(const u16x8*)&as[(wm + mi * 16 + l15) * 32 + lg * 8]);
    for (int ni = 0; ni < 4; ++ni)
      bfn[ni] = asbf(*(const u16x8*)&bs[(wn + ni * 16 + l15) * 32 + lg * 8]);
    for (int mi = 0; mi < MI; ++mi)
      for (int ni = 0; ni < 4; ++ni)
        acc[mi][ni] = __builtin_amdgcn_mfma_f32_16x16x32_bf16(af[mi], bfn[ni], acc[mi][ni], 0, 0, 0);
  };

  stage(0, 0);
  __syncthreads();
  int ntk = Ksub >> 5, cur = 0;
  for (int t = 0; t < ntk - 1; ++t) {
    stage(cur ^ 1, (t + 1) << 5);
    compute(cur);
    __syncthreads();
    cur ^= 1;
  }
  compute(cur);

  float* Cf = (kh == 0) ? CfA : CfB;
  const bool addb = (kh == 0);
  for (int p = 0; p < BM / 64; ++p) {
    __syncthreads();
    if ((wm >> 6) == p) {
      int rb = wm & 63;
      for (int mi = 0; mi < MI; ++mi)
        for (int ni = 0; ni < 4; ++ni) {
          int cn = wn + ni * 16 + l15;
          float bv = addb ? bias[n0 + cn] : 0.f;
          for (int r = 0; r < 4; ++r) {
            float vv = acc[mi][ni][r] + bv;
            if (EPI == 1) vv = 0.5f * vv * (1.f + erff(vv * 0.70710678118f));
            Cs[(rb + mi * 16 + 4 * lg + r) * 130 + cn] = vv;
          }
        }
    }
    __syncthreads();
    int row = tid >> 3;
    for (int ri = 0; ri < 2; ++ri) {
      int lr = ri * 32 + row;
      size_t gbase = (size_t)(m0 + p * 64 + lr) * ldc + n0;
      if (EPI == 0) {
        int c4 = (tid & 7) * 4;
        for (int j = 0; j < 4; ++j)
          *(f32x4*)(Cf + gbase + c4 + j * 32) = *(const f32x4*)&Cs[lr * 130 + c4 + j * 32];
      } else {
        for (int j = 0; j < 2; ++j) {
          int cc = (tid & 7) * 8 + j * 64;
          f32x4 v0 = *(const f32x4*)&Cs[lr * 130 + cc];
          f32x4 v1 = *(const f32x4*)&Cs[lr * 130 + cc + 4];
          u16x8 o;
          for (int i = 0; i < 4; ++i) { o[i] = f2bf(v0[i]); o[i + 4] = f2bf(v1[i]); }
          *(u16x8*)(Cb + gbase + cc) = o;
        }
      }
    }
  }
}

// ---------------------------------------------------------------- 256x256 deep-pipelined GEMM (logits)
// C = A @ B^T + bias. A:[2048,K] bf16, B:[N,K] bf16, C f32. grid = 8*(N/256), 512 thr.
// BK=32, 4-slot circular LDS (A: 4x8192 elems @0, B: @32768). Stage tile t+3 during tile t.
// Swizzle: 16B-block x' = x ^ ((row>>1)&3)  (2-way conflicts = free), inverse on global source.
__global__ __launch_bounds__(512, 2) void gemm256_kernel(
    const unsigned short* __restrict__ A, int lda,
    const unsigned short* __restrict__ B, int ldb,
    const float* __restrict__ bias, float* __restrict__ C, int ldc, int K) {
  extern __shared__ unsigned short sm[];      // 65536 elems = 128 KiB
  int b = blockIdx.x;
  int c = (int)gridDim.x >> 3;
  int wg = (b & 7) * c + (b >> 3);            // XCD-contiguous
  int mt = wg & 7, nt = wg >> 3;
  int m0 = mt * 256, n0 = nt * 256;

  int tid = threadIdx.x, ln = tid & 63, wv = tid >> 6;
  int l15 = ln & 15, lg = ln >> 4;
  int wm = wv >> 2, wn = wv & 3;              // 2M x 4N waves; wave tile 128x64

  // staging: thread -> dest row tid>>2 (128-row chunk), 16B-block tid&3; source pre-swizzled
  int srow = tid >> 2, sx = (tid & 3) ^ ((srow >> 1) & 3);
  const unsigned short* Ab = A + (size_t)(m0 + srow) * lda + sx * 8;
  const unsigned short* Bb = B + (size_t)(n0 + srow) * ldb + sx * 8;
  auto stA = [&](int t, int j) {              // j: row-chunk 0/1 (128 rows each)
    gload16(Ab + (size_t)j * 128 * lda + t * 32, &sm[(t & 3) * 8192 + j * 4096 + wv * 512]);
  };
  auto stB = [&](int t, int j) {
    gload16(Bb + (size_t)j * 128 * ldb + t * 32, &sm[32768 + (t & 3) * 8192 + j * 4096 + wv * 512]);
  };

  auto ldsA = [&](int t, int mi) -> bf16x8 {
    int row = wm * 128 + mi * 16 + l15;
    return asbf(*(const u16x8*)&sm[(t & 3) * 8192 + row * 32 + (lg ^ ((row >> 1) & 3)) * 8]);
  };
  auto ldsB = [&](int t, int ni) -> bf16x8 {
    int row = wn * 64 + ni * 16 + l15;
    return asbf(*(const u16x8*)&sm[32768 + (t & 3) * 8192 + row * 32 + (lg ^ ((row >> 1) & 3)) * 8]);
  };

  f32x4 acc[8][4] = {};
  bf16x8 Bfr[4];

#define PH_BAR() __builtin_amdgcn_sched_barrier(0); __builtin_amdgcn_s_barrier(); \
  asm volatile("s_waitcnt lgkmcnt(0)" ::: "memory"); __builtin_amdgcn_sched_barrier(0)
#define PH_END() __builtin_amdgcn_sched_barrier(0); __builtin_amdgcn_s_barrier()

  // prologue: stage tiles 0,1,2 (12 gloads); tile 0 resident at vmcnt(8)
  stA(0, 0); stA(0, 1); stB(0, 0); stB(0, 1);
  stA(1, 0); stA(1, 1); stB(1, 0); stB(1, 1);
  stA(2, 0); stA(2, 1); stB(2, 0); stB(2, 1);
  asm volatile("s_waitcnt vmcnt(8)" ::: "memory");
  __builtin_amdgcn_s_barrier();

  int ntk = K >> 5;
  for (int t = 0; t < ntk; ++t) {
    bool pf = (t + 3 < ntk);
    { // phase A: B frags (reused both phases) + A mi0-3; stage A(t+3)
      Bfr[0] = ldsB(t, 0); Bfr[1] = ldsB(t, 1); Bfr[2] = ldsB(t, 2); Bfr[3] = ldsB(t, 3);
      bf16x8 a0 = ldsA(t, 0), a1 = ldsA(t, 1), a2 = ldsA(t, 2), a3 = ldsA(t, 3);
      if (pf) { stA(t + 3, 0); stA(t + 3, 1); }
      PH_BAR();
      __builtin_amdgcn_s_setprio(1);
#pragma unroll
      for (int ni = 0; ni < 4; ++ni) {
        acc[0][ni] = __builtin_amdgcn_mfma_f32_16x16x32_bf16(a0, Bfr[ni], acc[0][ni], 0, 0, 0);
        acc[1][ni] = __builtin_amdgcn_mfma_f32_16x16x32_bf16(a1, Bfr[ni], acc[1][ni], 0, 0, 0);
        acc[2][ni] = __builtin_amdgcn_mfma_f32_16x16x32_bf16(a2, Bfr[ni], acc[2][ni], 0, 0, 0);
        acc[3][ni] = __builtin_amdgcn_mfma_f32_16x16x32_bf16(a3, Bfr[ni], acc[3][ni], 0, 0, 0);
      }
      __builtin_amdgcn_s_setprio(0);
      PH_END();
    }
    { // phase B: A mi4-7; stage B(t+3); tile-boundary counted vmcnt (tile t+1 resident)
      bf16x8 a4 = ldsA(t, 4), a5 = ldsA(t, 5), a6 = ldsA(t, 6), a7 = ldsA(t, 7);
      if (pf) { stB(t + 3, 0); stB(t + 3, 1); }
      if (t + 3 < ntk)       { asm volatile("s_waitcnt vmcnt(8)" ::: "memory"); }
      else if (t + 3 == ntk) { asm volatile("s_waitcnt vmcnt(4)" ::: "memory"); }
      else if (t + 2 == ntk) { asm volatile("s_waitcnt vmcnt(0)" ::: "memory"); }
      PH_BAR();
      __builtin_amdgcn_s_setprio(1);
#pragma unroll
      for (int ni = 0; ni < 4; ++ni) {
        acc[4][ni] = __builtin_amdgcn_mfma_f32_16x16x32_bf16(a4, Bfr[ni], acc[4][ni], 0, 0, 0);
        acc[5][ni] = __builtin_amdgcn_mfma_f32_16x16x32_bf16(a5, Bfr[ni], acc[5][ni], 0, 0, 0);
        acc[6][ni] = __builtin_amdgcn_mfma_f32_16x16x32_bf16(a6, Bfr[ni], acc[6][ni], 0, 0, 0);
        acc[7][ni] = __builtin_amdgcn_mfma_f32_16x16x32_bf16(a7, Bfr[ni], acc[7][ni], 0, 0, 0);
      }
      __builtin_amdgcn_s_setprio(0);
      PH_END();
    }
  }
#undef PH_BAR
#undef PH_END

  // epilogue: bias + direct stores
#pragma unroll
  for (int ni = 0; ni < 4; ++ni) {
    int col = n0 + wn * 64 + ni * 16 + l15;
    float bv = bias[col];
#pragma unroll
    for (int mi = 0; mi < 8; ++mi) {
      int row = m0 + wm * 128 + mi * 16 + lg * 4;
#pragma unroll
      for (int r = 0; r < 4; ++r)
        C[(size_t)(row + r) * ldc + col] = acc[mi][ni][r] + bv;
    }
  }
}

// ----------------------------------------------------------------
extern "C" void kernel_launch(void* const* d_in, const int* in_sizes, int n_in,
                              void* d_out, int out_size, void* d_ws, size_t ws_size,
                              hipStream_t stream) {
  const int* x = (const int*)d_in[0];
  const float* tok = (const float*)d_in[1];
  const float* pos = (const float*)d_in[2];
  const float* wq = (const float*)d_in[3];
  const float* wk = (const float*)d_in[4];
  const float* wv = (const float*)d_in[5];
  const float* wo = (const float*)d_in[6];
  const float* bo = (const float*)d_in[7];
  const float* ln1g = (const float*)d_in[8];
  const float* ln1b = (const float*)d_in[9];
  const float* ln2g = (const float*)d_in[10];
  const float* ln2b = (const float*)d_in[11];
  const float* w1 = (const float*)d_in[12];
  const float* b1 = (const float*)d_in[13];
  const float* w2 = (const float*)d_in[14];
  const float* b2 = (const float*)d_in[15];
  const float* outw = (const float*)d_in[16];
  const float* outb = (const float*)d_in[17];
  float* out = (float*)d_out;

  const size_t MiB = 1 << 20;
  const size_t need = 4 * MiB + 65536000;
  if (ws_size < need) return;
  char* base = (char*)d_ws;
  unsigned short* hbf = (unsigned short*)base;            // 4 MiB, persistent
  char* R = base + 4 * MiB;
  float* hf  = (float*)(R);                               // 8 MiB
  float* x1f = (float*)(R + 8 * MiB);                     // 8 MiB
  unsigned short* x1bf = (unsigned short*)(R + 16 * MiB); // 4 MiB
  float* cfA = (float*)(R + 20 * MiB);                    // 8 MiB
  float* cfB = (float*)(R + 28 * MiB);                    // 8 MiB
  unsigned short* qs = (unsigned short*)(R + 36 * MiB);   // 6 slots x 4 MiB
  const size_t SL = 2048ull * 1024;
  unsigned short* qbf = qs;
  unsigned short* kbf = qs + SL;
  unsigned short* vbf = qs + 2 * SL;                      // also attn-out
  unsigned short* vtbf = qs + 3 * SL;                     // also wobf
  unsigned short* wobf = vtbf;
  unsigned short* w1bf = qbf;
  unsigned short* w2bf = qbf;
  unsigned short* ffbf = vbf;
  unsigned short* outwbf = (unsigned short*)R;            // 62.5 MiB, after layers

  embed_kernel<<<2048, 256, 0, stream>>>(x, tok, pos, hf, hbf);
  for (int l = 0; l < 4; ++l) {
    qkv_kernel<<<1024, 256, 0, stream>>>(hbf, wq + l * 4096, wk + l * 4096, wv + l * 4096,
                                         qbf, kbf, vbf);
    vtrans_kernel<<<dim3(16, 32), 256, 0, stream>>>(vbf, vtbf);
    attn_kernel<<<dim3(16, 32), 256, 0, stream>>>(qbf, kbf, vtbf, vbf);
    cvt_kernel<<<512, 256, 0, stream>>>(wo + (size_t)l * 1048576, wobf, 131072);
    cvt_kernel<<<2048, 256, 0, stream>>>(w1 + (size_t)l * 4194304, w1bf, 524288);
    gemm_kernel<64, 2, 0><<<512, 256, 0, stream>>>(
        vbf, 1024, wobf, 1024, bo + l * 1024, cfA, cfB, nullptr, 1024, 512);
    ln_kernel<<<2048, 256, 0, stream>>>(cfA, cfB, hf, ln1g + l * 1024, ln1b + l * 1024,
                                        x1f, x1bf);
    gemm_kernel<128, 1, 1><<<512, 256, 0, stream>>>(
        x1bf, 1024, w1bf, 1024, b1 + l * 4096, nullptr, nullptr, ffbf, 4096, 1024);
    cvt_kernel<<<2048, 256, 0, stream>>>(w2 + (size_t)l * 4194304, w2bf, 524288);
    gemm_kernel<64, 2, 0><<<512, 256, 0, stream>>>(
        ffbf, 4096, w2bf, 4096, b2 + l * 1024, cfA, cfB, nullptr, 1024, 2048);
    ln_kernel<<<2048, 256, 0, stream>>>(cfA, cfB, x1f, ln2g + l * 1024, ln2b + l * 1024,
                                        hf, hbf);
  }
  cvt_kernel<<<2048, 256, 0, stream>>>(outw, outwbf, 4096000);
  gemm256_kernel<<<1000, 512, 131072, stream>>>(hbf, 1024, outwbf, 1024, outb, out, 32000, 1024);
}